// Round 11
// baseline (305.170 us; speedup 1.0000x reference)
//
#include <hip/hip_runtime.h>

#define NN 30000
#define NE 120000
#define NG 938   // ceil(NN/32)
#define TPB 256
#define SB 118   // ceil(NN/256) scan blocks

__device__ __forceinline__ float blo(unsigned u) { return __uint_as_float(u << 16); }
__device__ __forceinline__ float bhi(unsigned u) { return __uint_as_float(u & 0xffff0000u); }

__device__ __forceinline__ unsigned short f2b(float f) {
  unsigned u = __float_as_uint(f);
  return (unsigned short)((u + 0x7fff + ((u >> 16) & 1)) >> 16);  // RNE
}

__global__ void k_zero(int* __restrict__ cnt) {
  int n = blockIdx.x * TPB + threadIdx.x;
  if (n < NN) cnt[n] = 0;
}

// one-time: pre-transposed + pre-swizzled weights Wt[(k*1024+o*32+i)^((o&7)<<2)]
__global__ void k_wprep(const float* __restrict__ kw2, const float* __restrict__ kb2,
                        const float* __restrict__ root, float* __restrict__ Wt) {
  int f = blockIdx.x * TPB + threadIdx.x;
  if (f >= 10240) return;
  int k = f >> 10, rem = f & 1023, i = rem >> 5, o = rem & 31;
  float v;
  if (f < 8192) v = kw2[f];
  else if (f < 9216) v = kb2[f - 8192];
  else v = root[f - 9216];
  Wt[(k * 1024 + o * 32 + i) ^ ((o & 7) << 2)] = v;
}

// kc[e*8+k] = relu(ea@k_w1+k_b1); cnt[dst]++
__global__ void k_prep(const float* __restrict__ ea, const float* __restrict__ w1,
                       const float* __restrict__ b1, const int* __restrict__ dst,
                       float* __restrict__ kc, int* __restrict__ cnt) {
  int e = blockIdx.x * TPB + threadIdx.x;
  if (e >= NE) return;
  float a[6];
#pragma unroll
  for (int i = 0; i < 6; i++) a[i] = ea[e * 6 + i];
#pragma unroll
  for (int k = 0; k < 8; k++) {
    float s = b1[k];
#pragma unroll
    for (int i = 0; i < 6; i++) s = fmaf(a[i], w1[i * 8 + k], s);
    kc[e * 8 + k] = fmaxf(s, 0.f);
  }
  atomicAdd(&cnt[dst[e]], 1);
}

// 3-phase parallel scan
__global__ void k_scan1(const int* __restrict__ cnt, int* __restrict__ bsum) {
  __shared__ int S[TPB];
  int t = threadIdx.x, n = blockIdx.x * TPB + t;
  S[t] = (n < NN) ? cnt[n] : 0;
  __syncthreads();
  for (int off = TPB / 2; off; off >>= 1) {
    if (t < off) S[t] += S[t + off];
    __syncthreads();
  }
  if (t == 0) bsum[blockIdx.x] = S[0];
}

__global__ void k_scan2(int* __restrict__ bsum) {
  __shared__ int S[128];
  int t = threadIdx.x;
  S[t] = (t < SB) ? bsum[t] : 0;
  __syncthreads();
  for (int off = 1; off < 128; off <<= 1) {
    int v = S[t] + ((t >= off) ? S[t - off] : 0);
    __syncthreads();
    S[t] = v;
    __syncthreads();
  }
  if (t < SB) bsum[t] = (t > 0) ? S[t - 1] : 0;
}

__global__ void k_scan3(const int* __restrict__ cnt, const int* __restrict__ bsum,
                        int* __restrict__ rowstart, int* __restrict__ wpos,
                        float* __restrict__ icnt) {
  __shared__ int S[TPB];
  int t = threadIdx.x, n = blockIdx.x * TPB + t;
  int c = (n < NN) ? cnt[n] : 0;
  S[t] = c;
  __syncthreads();
  for (int off = 1; off < TPB; off <<= 1) {
    int v = S[t] + ((t >= off) ? S[t - off] : 0);
    __syncthreads();
    S[t] = v;
    __syncthreads();
  }
  if (n < NN) {
    int r = bsum[blockIdx.x] + S[t] - c;  // exclusive prefix
    rowstart[n] = r;
    wpos[n] = r;
    icnt[n] = 1.f / (float)max(c, 1);
  }
}

// scatter edge payloads into dst-sorted slots: srcs[pos], kcs[pos*8..]
__global__ void k_scatter(const int* __restrict__ dst, const int* __restrict__ src,
                          const float* __restrict__ kc, int* __restrict__ wpos,
                          int* __restrict__ srcs, float* __restrict__ kcs) {
  int e = blockIdx.x * TPB + threadIdx.x;
  if (e >= NE) return;
  int pos = atomicAdd(&wpos[dst[e]], 1);
  srcs[pos] = src[e];
  float4 a = *(const float4*)&kc[e * 8];
  float4 b = *(const float4*)&kc[e * 8 + 4];
  *(float4*)&kcs[(size_t)pos * 8] = a;
  *(float4*)&kcs[(size_t)pos * 8 + 4] = b;
}

// Fused layer: CSR-aggregate (or fc1 for FIRST) -> hL in LDS -> R8-shape transform.
// P layout: Pb4u[n][kp][o] dwords (kp=0..3, bf16 pair k=2kp,2kp+1), Pb1[n][o] (k=8),
// Pr[n][o] (root, f32). Transform body is R8-verified spill-free: hv arrays scoped
// inside pp iteration, unroll-1 kp loop, per-kp immediate full-line dword stores.
template <int FIRST>
__global__ __launch_bounds__(TPB, 3) void k_layer(
    const float* __restrict__ x, const float* __restrict__ fc1w,
    const float* __restrict__ fc1b, const float* __restrict__ Wt,
    const int* __restrict__ rowstart, const int* __restrict__ cnt,
    const float* __restrict__ icnt, const int* __restrict__ srcs,
    const float* __restrict__ kcs, const float* __restrict__ cbias,
    const unsigned* __restrict__ Pb4i, const unsigned* __restrict__ Pb1i,
    const float* __restrict__ Pri, unsigned* __restrict__ Pb4o,
    unsigned* __restrict__ Pb1o, float* __restrict__ Pro) {
  __shared__ float Wl[10 * 1024];
  __shared__ float hL[1024];
  const int tid = threadIdx.x;
  const int base = blockIdx.x * 32;
  {  // linear conflict-free staging from pre-swizzled Wt
    const float4* Ws = (const float4*)Wt;
    float4* Wd = (float4*)Wl;
    for (int f = tid; f < 2560; f += TPB) Wd[f] = Ws[f];
  }
  const int g = tid >> 5, o = tid & 31;
  if (FIRST) {
    for (int e2 = tid; e2 < 1024; e2 += TPB) {
      int ln = e2 >> 5, oo = e2 & 31, n = base + ln;
      hL[e2] = (n < NN) ? fmaf(x[n], fc1w[oo], fc1b[oo]) : 0.f;
    }
  } else {
    for (int q = 0; q < 4; q++) {
      int ln = q * 8 + g;
      int n = base + ln;
      int rs = 0, re = 0;
      if (n < NN) { rs = rowstart[n]; re = rs + cnt[n]; }
      float acc = 0.f;
      for (int j = rs; j < re; j++) {
        int s = srcs[j];
        float ck = (o < 8) ? kcs[(size_t)j * 8 + o] : 0.f;
        const unsigned* Ps = Pb4i + (size_t)s * 128;
        unsigned w0 = Ps[o], w1 = Ps[32 + o], w2 = Ps[64 + o], w3 = Ps[96 + o];
        unsigned wb = Pb1i[(size_t)s * 32 + o];
        acc += blo(wb);  // bias row, coefficient 1
        acc = fmaf(__shfl(ck, 0, 32), blo(w0), acc);
        acc = fmaf(__shfl(ck, 1, 32), bhi(w0), acc);
        acc = fmaf(__shfl(ck, 2, 32), blo(w1), acc);
        acc = fmaf(__shfl(ck, 3, 32), bhi(w1), acc);
        acc = fmaf(__shfl(ck, 4, 32), blo(w2), acc);
        acc = fmaf(__shfl(ck, 5, 32), bhi(w2), acc);
        acc = fmaf(__shfl(ck, 6, 32), blo(w3), acc);
        acc = fmaf(__shfl(ck, 7, 32), bhi(w3), acc);
      }
      float hv = 0.f;
      if (n < NN)
        hv = fmaxf(fmaf(acc, icnt[n], Pri[(size_t)n * 32 + o] + cbias[o]), 0.f);
      hL[ln * 32 + o] = hv;
    }
  }
  __syncthreads();
  // ---- transform (R8 body) ----
  const int sw = (o & 7) << 2;
#pragma unroll
  for (int pp = 0; pp < 2; pp++) {
    const int ln0 = pp * 16 + g, ln1 = ln0 + 8;
    const int n0 = base + ln0, n1 = base + ln1;
    float4 hv0[8], hv1[8];
#pragma unroll
    for (int c = 0; c < 8; c++) {
      hv0[c] = *(const float4*)&hL[ln0 * 32 + c * 4];
      hv1[c] = *(const float4*)&hL[ln1 * 32 + c * 4];
    }
#pragma unroll 1
    for (int kp = 0; kp < 5; kp++) {
      float aA0 = 0.f, aB0 = 0.f, aA1 = 0.f, aB1 = 0.f;
#pragma unroll
      for (int c = 0; c < 8; c++) {
        const int idx = o * 32 + ((c << 2) ^ sw);
        const float4 wA = *(const float4*)&Wl[(2 * kp) * 1024 + idx];
        const float4 wB = *(const float4*)&Wl[(2 * kp + 1) * 1024 + idx];
        aA0 = fmaf(hv0[c].x, wA.x, aA0); aA1 = fmaf(hv1[c].x, wA.x, aA1);
        aB0 = fmaf(hv0[c].x, wB.x, aB0); aB1 = fmaf(hv1[c].x, wB.x, aB1);
        aA0 = fmaf(hv0[c].y, wA.y, aA0); aA1 = fmaf(hv1[c].y, wA.y, aA1);
        aB0 = fmaf(hv0[c].y, wB.y, aB0); aB1 = fmaf(hv1[c].y, wB.y, aB1);
        aA0 = fmaf(hv0[c].z, wA.z, aA0); aA1 = fmaf(hv1[c].z, wA.z, aA1);
        aB0 = fmaf(hv0[c].z, wB.z, aB0); aB1 = fmaf(hv1[c].z, wB.z, aB1);
        aA0 = fmaf(hv0[c].w, wA.w, aA0); aA1 = fmaf(hv1[c].w, wA.w, aA1);
        aB0 = fmaf(hv0[c].w, wB.w, aB0); aB1 = fmaf(hv1[c].w, wB.w, aB1);
      }
      if (kp < 4) {
        if (n0 < NN)
          Pb4o[(size_t)n0 * 128 + kp * 32 + o] =
              f2b(aA0) | ((unsigned)f2b(aB0) << 16);
        if (n1 < NN)
          Pb4o[(size_t)n1 * 128 + kp * 32 + o] =
              f2b(aA1) | ((unsigned)f2b(aB1) << 16);
      } else {  // 2*kp = 8 -> bias row; 2*kp+1 = 9 -> root
        if (n0 < NN) {
          Pb1o[(size_t)n0 * 32 + o] = f2b(aA0);
          Pro[(size_t)n0 * 32 + o] = aB0;
        }
        if (n1 < NN) {
          Pb1o[(size_t)n1 * 32 + o] = f2b(aA1);
          Pro[(size_t)n1 * 32 + o] = aB1;
        }
      }
    }
  }
}

// final: aggregate -> h -> out = h @ fc2w + fc2b  (no LDS, high occupancy)
__global__ void k_final(const int* __restrict__ rowstart, const int* __restrict__ cnt,
                        const float* __restrict__ icnt, const int* __restrict__ srcs,
                        const float* __restrict__ kcs,
                        const unsigned* __restrict__ Pb4u,
                        const unsigned* __restrict__ Pb1, const float* __restrict__ Pr,
                        const float* __restrict__ cbias, const float* __restrict__ fc2w,
                        const float* __restrict__ fc2b, float* __restrict__ out) {
  int t = blockIdx.x * TPB + threadIdx.x;
  int n = t >> 5, o = t & 31;
  if (n >= NN) return;
  int rs = rowstart[n], re = rs + cnt[n];
  float acc = 0.f;
  for (int j = rs; j < re; j++) {
    int s = srcs[j];
    float ck = (o < 8) ? kcs[(size_t)j * 8 + o] : 0.f;
    const unsigned* Ps = Pb4u + (size_t)s * 128;
    unsigned w0 = Ps[o], w1 = Ps[32 + o], w2 = Ps[64 + o], w3 = Ps[96 + o];
    unsigned wb = Pb1[(size_t)s * 32 + o];
    acc += blo(wb);
    acc = fmaf(__shfl(ck, 0, 32), blo(w0), acc);
    acc = fmaf(__shfl(ck, 1, 32), bhi(w0), acc);
    acc = fmaf(__shfl(ck, 2, 32), blo(w1), acc);
    acc = fmaf(__shfl(ck, 3, 32), bhi(w1), acc);
    acc = fmaf(__shfl(ck, 4, 32), blo(w2), acc);
    acc = fmaf(__shfl(ck, 5, 32), bhi(w2), acc);
    acc = fmaf(__shfl(ck, 6, 32), blo(w3), acc);
    acc = fmaf(__shfl(ck, 7, 32), bhi(w3), acc);
  }
  float hv = fmaxf(fmaf(acc, icnt[n], Pr[(size_t)n * 32 + o] + cbias[o]), 0.f);
  float s2 = hv * fc2w[o];
#pragma unroll
  for (int d = 16; d; d >>= 1) s2 += __shfl_xor(s2, d, 32);
  if (o == 0) out[n] = s2 + fc2b[0];
}

extern "C" void kernel_launch(void* const* d_in, const int* in_sizes, int n_in,
                              void* d_out, int out_size, void* d_ws, size_t ws_size,
                              hipStream_t stream) {
  const float* x     = (const float*)d_in[0];
  const int*   ei    = (const int*)d_in[1];
  const float* ea    = (const float*)d_in[2];
  const float* fc1w  = (const float*)d_in[3];
  const float* fc1b  = (const float*)d_in[4];
  const float* kw1   = (const float*)d_in[5];
  const float* kb1   = (const float*)d_in[6];
  const float* kw2   = (const float*)d_in[7];
  const float* kb2   = (const float*)d_in[8];
  const float* root  = (const float*)d_in[9];
  const float* cbias = (const float*)d_in[10];
  const float* fc2w  = (const float*)d_in[11];
  const float* fc2b  = (const float*)d_in[12];
  float* out = (float*)d_out;
  const int* srcp = ei;
  const int* dstp = ei + NE;

  float* ws = (float*)d_ws;
  float* kc       = ws;                        // NE*8
  float* kcs      = kc + NE * 8;               // NE*8
  int*   srcs     = (int*)(kcs + NE * 8);      // NE
  float* icnt     = (float*)(srcs + NE);       // NN
  float* Pr0      = icnt + NN;                 // NN*32
  float* Pr1      = Pr0 + NN * 32;             // NN*32
  int*   cnt      = (int*)(Pr1 + NN * 32);     // NN
  int*   rowstart = cnt + NN;                  // NN
  int*   wpos     = rowstart + NN;             // NN
  int*   bsum     = wpos + NN;                 // 128
  float* Wt       = (float*)(bsum + 128);      // 10240
  unsigned* Pb4_0 = (unsigned*)(Wt + 10240);   // NN*128
  unsigned* Pb4_1 = Pb4_0 + (size_t)NN * 128;  // NN*128
  unsigned* Pb1_0 = Pb4_1 + (size_t)NN * 128;  // NN*32
  unsigned* Pb1_1 = Pb1_0 + (size_t)NN * 32;   // NN*32

  k_zero<<<(NN + TPB - 1) / TPB, TPB, 0, stream>>>(cnt);
  k_wprep<<<40, TPB, 0, stream>>>(kw2, kb2, root, Wt);
  k_prep<<<(NE + TPB - 1) / TPB, TPB, 0, stream>>>(ea, kw1, kb1, dstp, kc, cnt);
  k_scan1<<<SB, TPB, 0, stream>>>(cnt, bsum);
  k_scan2<<<1, 128, 0, stream>>>(bsum);
  k_scan3<<<SB, TPB, 0, stream>>>(cnt, bsum, rowstart, wpos, icnt);
  k_scatter<<<(NE + TPB - 1) / TPB, TPB, 0, stream>>>(dstp, srcp, kc, wpos, srcs, kcs);

  k_layer<1><<<NG, TPB, 0, stream>>>(x, fc1w, fc1b, Wt, rowstart, cnt, icnt, srcs,
                                     kcs, cbias, Pb4_0, Pb1_0, Pr0,
                                     Pb4_0, Pb1_0, Pr0);
  k_layer<0><<<NG, TPB, 0, stream>>>(x, fc1w, fc1b, Wt, rowstart, cnt, icnt, srcs,
                                     kcs, cbias, Pb4_0, Pb1_0, Pr0,
                                     Pb4_1, Pb1_1, Pr1);
  k_layer<0><<<NG, TPB, 0, stream>>>(x, fc1w, fc1b, Wt, rowstart, cnt, icnt, srcs,
                                     kcs, cbias, Pb4_1, Pb1_1, Pr1,
                                     Pb4_0, Pb1_0, Pr0);
  k_layer<0><<<NG, TPB, 0, stream>>>(x, fc1w, fc1b, Wt, rowstart, cnt, icnt, srcs,
                                     kcs, cbias, Pb4_0, Pb1_0, Pr0,
                                     Pb4_1, Pb1_1, Pr1);
  k_final<<<(NN * 32 + TPB - 1) / TPB, TPB, 0, stream>>>(
      rowstart, cnt, icnt, srcs, kcs, Pb4_1, Pb1_1, Pr1, cbias, fc2w, fc2b, out);
}

// Round 12
// 158.100 us; speedup vs baseline: 1.9302x; 1.9302x over previous
//
#include <hip/hip_runtime.h>

#define NN 30000
#define NE 120000
#define TPB 256
#define SB 118   // ceil(NN/256) scan blocks
#define NW 1875  // node tiles of 16 (NN/16 exact)

typedef __attribute__((ext_vector_type(8))) __bf16 bf16x8;
typedef __attribute__((ext_vector_type(4))) float f32x4;

union B8 { bf16x8 b; unsigned short u[8]; uint4 q; };

__device__ __forceinline__ float blo(unsigned u) { return __uint_as_float(u << 16); }
__device__ __forceinline__ float bhi(unsigned u) { return __uint_as_float(u & 0xffff0000u); }

__device__ __forceinline__ unsigned short f2b(float f) {
  unsigned u = __float_as_uint(f);
  return (unsigned short)((u + 0x7fff + ((u >> 16) & 1)) >> 16);  // RNE
}

__global__ void k_zero(int* __restrict__ cnt) {
  int n = blockIdx.x * TPB + threadIdx.x;
  if (n < NN) cnt[n] = 0;
}

// one-time: pack W'[32 x 320] (j = k*32+o; k=0..7 kw2, 8 kb2, 9 root) into
// MFMA B-fragments, bf16. Fragment ct covers cols ct*16..+15; lane l holds
// B[(l>>4)*8 + ii][ct*16 + (l&15)], ii=0..7, as one uint4.
__global__ void k_wprep(const float* __restrict__ kw2, const float* __restrict__ kb2,
                        const float* __restrict__ root, uint4* __restrict__ Wb) {
  int f = blockIdx.x * TPB + threadIdx.x;
  if (f >= 1280) return;
  int ct = f >> 6, l = f & 63;
  int j = ct * 16 + (l & 15);
  int k = j >> 5, o = j & 31;
  int i0 = (l >> 4) * 8;
  B8 w;
#pragma unroll
  for (int ii = 0; ii < 8; ii++) {
    int i = i0 + ii;
    float v;
    if (k < 8) v = kw2[k * 1024 + i * 32 + o];
    else if (k == 8) v = kb2[i * 32 + o];
    else v = root[i * 32 + o];
    w.u[ii] = f2b(v);
  }
  Wb[f] = w.q;
}

// kc[e*8+k] = relu(ea@k_w1+k_b1); cnt[dst]++
__global__ void k_prep(const float* __restrict__ ea, const float* __restrict__ w1,
                       const float* __restrict__ b1, const int* __restrict__ dst,
                       float* __restrict__ kc, int* __restrict__ cnt) {
  int e = blockIdx.x * TPB + threadIdx.x;
  if (e >= NE) return;
  float a[6];
#pragma unroll
  for (int i = 0; i < 6; i++) a[i] = ea[e * 6 + i];
#pragma unroll
  for (int k = 0; k < 8; k++) {
    float s = b1[k];
#pragma unroll
    for (int i = 0; i < 6; i++) s = fmaf(a[i], w1[i * 8 + k], s);
    kc[e * 8 + k] = fmaxf(s, 0.f);
  }
  atomicAdd(&cnt[dst[e]], 1);
}

// 3-phase parallel scan
__global__ void k_scan1(const int* __restrict__ cnt, int* __restrict__ bsum) {
  __shared__ int S[TPB];
  int t = threadIdx.x, n = blockIdx.x * TPB + t;
  S[t] = (n < NN) ? cnt[n] : 0;
  __syncthreads();
  for (int off = TPB / 2; off; off >>= 1) {
    if (t < off) S[t] += S[t + off];
    __syncthreads();
  }
  if (t == 0) bsum[blockIdx.x] = S[0];
}

__global__ void k_scan2(int* __restrict__ bsum) {
  __shared__ int S[128];
  int t = threadIdx.x;
  S[t] = (t < SB) ? bsum[t] : 0;
  __syncthreads();
  for (int off = 1; off < 128; off <<= 1) {
    int v = S[t] + ((t >= off) ? S[t - off] : 0);
    __syncthreads();
    S[t] = v;
    __syncthreads();
  }
  if (t < SB) bsum[t] = (t > 0) ? S[t - 1] : 0;
}

__global__ void k_scan3(const int* __restrict__ cnt, const int* __restrict__ bsum,
                        int* __restrict__ rowstart, int* __restrict__ wpos,
                        float* __restrict__ icnt) {
  __shared__ int S[TPB];
  int t = threadIdx.x, n = blockIdx.x * TPB + t;
  int c = (n < NN) ? cnt[n] : 0;
  S[t] = c;
  __syncthreads();
  for (int off = 1; off < TPB; off <<= 1) {
    int v = S[t] + ((t >= off) ? S[t - off] : 0);
    __syncthreads();
    S[t] = v;
    __syncthreads();
  }
  if (n < NN) {
    int r = bsum[blockIdx.x] + S[t] - c;  // exclusive prefix
    rowstart[n] = r;
    wpos[n] = r;
    icnt[n] = 1.f / (float)max(c, 1);
  }
}

// scatter edge payloads into dst-sorted slots: srcs[pos], kcs[pos*8..]
__global__ void k_scatter(const int* __restrict__ dst, const int* __restrict__ src,
                          const float* __restrict__ kc, int* __restrict__ wpos,
                          int* __restrict__ srcs, float* __restrict__ kcs) {
  int e = blockIdx.x * TPB + threadIdx.x;
  if (e >= NE) return;
  int pos = atomicAdd(&wpos[dst[e]], 1);
  srcs[pos] = src[e];
  float4 a = *(const float4*)&kc[e * 8];
  float4 b = *(const float4*)&kc[e * 8 + 4];
  *(float4*)&kcs[(size_t)pos * 8] = a;
  *(float4*)&kcs[(size_t)pos * 8 + 4] = b;
}

// MFMA node transform: one wave per 16 nodes. P = h[16x32] @ W'[32x320] via
// 20x mfma_f32_16x16x32_bf16 (K=32 consumed in one). No LDS. B-frags (80 VGPR)
// loaded once. D mapping (HW-verified m89): col=lane&15, row=(lane>>4)*4+reg.
// Output layout matches k_agg: Pb4[n][kp][o] dword = bf16(k=2kp) | bf16(k=2kp+1)<<16.
template <int FIRST>
__global__ __launch_bounds__(TPB, 4) void k_node(
    const float* __restrict__ x, const float* __restrict__ fc1w,
    const float* __restrict__ fc1b, const float* __restrict__ h,
    const uint4* __restrict__ Wb, unsigned* __restrict__ Pb4,
    unsigned* __restrict__ Pb1, float* __restrict__ Pr) {
  const int l = threadIdx.x & 63;
  const int wid = blockIdx.x * (TPB / 64) + (threadIdx.x >> 6);
  if (wid >= NW) return;
  const int nb = wid * 16;

  B8 Bf[20];
#pragma unroll
  for (int ct = 0; ct < 20; ct++) Bf[ct].q = Wb[ct * 64 + l];

  // A fragment: lane l holds h[nb + (l&15)][(l>>4)*8 + ii], ii=0..7
  const int row = nb + (l & 15);
  const int k0 = (l >> 4) * 8;
  B8 af;
  if (FIRST) {
    float xv = x[row];
#pragma unroll
    for (int ii = 0; ii < 8; ii++)
      af.u[ii] = f2b(fmaf(xv, fc1w[k0 + ii], fc1b[k0 + ii]));
  } else {
#pragma unroll
    for (int ii = 0; ii < 8; ii++) af.u[ii] = f2b(h[row * 32 + k0 + ii]);
  }

  const int oo = l & 15;
  const int r0 = (l >> 4) * 4;
#pragma unroll
  for (int kp = 0; kp < 4; kp++) {
    f32x4 d0 = {0.f, 0.f, 0.f, 0.f}, d1 = d0, d2 = d0, d3 = d0;
    d0 = __builtin_amdgcn_mfma_f32_16x16x32_bf16(af.b, Bf[4 * kp + 0].b, d0, 0, 0, 0);
    d1 = __builtin_amdgcn_mfma_f32_16x16x32_bf16(af.b, Bf[4 * kp + 1].b, d1, 0, 0, 0);
    d2 = __builtin_amdgcn_mfma_f32_16x16x32_bf16(af.b, Bf[4 * kp + 2].b, d2, 0, 0, 0);
    d3 = __builtin_amdgcn_mfma_f32_16x16x32_bf16(af.b, Bf[4 * kp + 3].b, d3, 0, 0, 0);
#pragma unroll
    for (int r = 0; r < 4; r++) {
      int n = nb + r0 + r;
      Pb4[(size_t)n * 128 + kp * 32 + oo] =
          f2b(d0[r]) | ((unsigned)f2b(d2[r]) << 16);
      Pb4[(size_t)n * 128 + kp * 32 + 16 + oo] =
          f2b(d1[r]) | ((unsigned)f2b(d3[r]) << 16);
    }
  }
  {  // ct 16/17: k=8 bias row -> Pb1; ct 18/19: k=9 root -> Pr (f32)
    f32x4 d0 = {0.f, 0.f, 0.f, 0.f}, d1 = d0, d2 = d0, d3 = d0;
    d0 = __builtin_amdgcn_mfma_f32_16x16x32_bf16(af.b, Bf[16].b, d0, 0, 0, 0);
    d1 = __builtin_amdgcn_mfma_f32_16x16x32_bf16(af.b, Bf[17].b, d1, 0, 0, 0);
    d2 = __builtin_amdgcn_mfma_f32_16x16x32_bf16(af.b, Bf[18].b, d2, 0, 0, 0);
    d3 = __builtin_amdgcn_mfma_f32_16x16x32_bf16(af.b, Bf[19].b, d3, 0, 0, 0);
#pragma unroll
    for (int r = 0; r < 4; r++) {
      int n = nb + r0 + r;
      Pb1[(size_t)n * 32 + oo] = f2b(d0[r]);
      Pb1[(size_t)n * 32 + 16 + oo] = f2b(d1[r]);
      Pr[(size_t)n * 32 + oo] = d2[r];
      Pr[(size_t)n * 32 + 16 + oo] = d3[r];
    }
  }
}

// CSR aggregate + activation (R9-verified). FINAL=0: writes h. FINAL=1: fc2 -> out.
template <int FINAL>
__global__ void k_agg(const int* __restrict__ rowstart, const int* __restrict__ cnt,
                      const float* __restrict__ icnt, const int* __restrict__ srcs,
                      const float* __restrict__ kcs,
                      const unsigned* __restrict__ Pb4u,
                      const unsigned* __restrict__ Pb1, const float* __restrict__ Pr,
                      const float* __restrict__ cbias, const float* __restrict__ fc2w,
                      const float* __restrict__ fc2b, float* __restrict__ h,
                      float* __restrict__ out) {
  int t = blockIdx.x * TPB + threadIdx.x;
  int n = t >> 5, o = t & 31;
  if (n >= NN) return;
  int rs = rowstart[n], re = rs + cnt[n];
  float acc = 0.f;
  for (int j = rs; j < re; j++) {
    int s = srcs[j];
    float ck = (o < 8) ? kcs[(size_t)j * 8 + o] : 0.f;
    const unsigned* Ps = Pb4u + (size_t)s * 128;
    unsigned w0 = Ps[o], w1 = Ps[32 + o], w2 = Ps[64 + o], w3 = Ps[96 + o];
    unsigned wb = Pb1[(size_t)s * 32 + o];
    acc += blo(wb);  // bias row, coefficient 1
    acc = fmaf(__shfl(ck, 0, 32), blo(w0), acc);
    acc = fmaf(__shfl(ck, 1, 32), bhi(w0), acc);
    acc = fmaf(__shfl(ck, 2, 32), blo(w1), acc);
    acc = fmaf(__shfl(ck, 3, 32), bhi(w1), acc);
    acc = fmaf(__shfl(ck, 4, 32), blo(w2), acc);
    acc = fmaf(__shfl(ck, 5, 32), bhi(w2), acc);
    acc = fmaf(__shfl(ck, 6, 32), blo(w3), acc);
    acc = fmaf(__shfl(ck, 7, 32), bhi(w3), acc);
  }
  float hv = fmaxf(fmaf(acc, icnt[n], Pr[(size_t)n * 32 + o] + cbias[o]), 0.f);
  if (FINAL) {
    float s2 = hv * fc2w[o];
#pragma unroll
    for (int d = 16; d; d >>= 1) s2 += __shfl_xor(s2, d, 32);
    if (o == 0) out[n] = s2 + fc2b[0];
  } else {
    h[(size_t)n * 32 + o] = hv;
  }
}

extern "C" void kernel_launch(void* const* d_in, const int* in_sizes, int n_in,
                              void* d_out, int out_size, void* d_ws, size_t ws_size,
                              hipStream_t stream) {
  const float* x     = (const float*)d_in[0];
  const int*   ei    = (const int*)d_in[1];
  const float* ea    = (const float*)d_in[2];
  const float* fc1w  = (const float*)d_in[3];
  const float* fc1b  = (const float*)d_in[4];
  const float* kw1   = (const float*)d_in[5];
  const float* kb1   = (const float*)d_in[6];
  const float* kw2   = (const float*)d_in[7];
  const float* kb2   = (const float*)d_in[8];
  const float* root  = (const float*)d_in[9];
  const float* cbias = (const float*)d_in[10];
  const float* fc2w  = (const float*)d_in[11];
  const float* fc2b  = (const float*)d_in[12];
  float* out = (float*)d_out;
  const int* srcp = ei;
  const int* dstp = ei + NE;

  float* ws = (float*)d_ws;
  float* kc       = ws;                        // NE*8
  float* kcs      = kc + NE * 8;               // NE*8
  int*   srcs     = (int*)(kcs + NE * 8);      // NE
  float* icnt     = (float*)(srcs + NE);       // NN
  float* h        = icnt + NN;                 // NN*32
  float* Pr       = h + NN * 32;               // NN*32
  int*   cnt      = (int*)(Pr + NN * 32);      // NN
  int*   rowstart = cnt + NN;                  // NN
  int*   wpos     = rowstart + NN;             // NN
  int*   bsum     = wpos + NN;                 // 128
  uint4* Wb       = (uint4*)(bsum + 128);      // 1280 uint4 (20KB), 16B-aligned
  unsigned* Pb4   = (unsigned*)(Wb + 1280);    // NN*128
  unsigned* Pb1   = Pb4 + (size_t)NN * 128;    // NN*32

  k_zero<<<(NN + TPB - 1) / TPB, TPB, 0, stream>>>(cnt);
  k_wprep<<<5, TPB, 0, stream>>>(kw2, kb2, root, Wb);
  k_prep<<<(NE + TPB - 1) / TPB, TPB, 0, stream>>>(ea, kw1, kb1, dstp, kc, cnt);
  k_scan1<<<SB, TPB, 0, stream>>>(cnt, bsum);
  k_scan2<<<1, 128, 0, stream>>>(bsum);
  k_scan3<<<SB, TPB, 0, stream>>>(cnt, bsum, rowstart, wpos, icnt);
  k_scatter<<<(NE + TPB - 1) / TPB, TPB, 0, stream>>>(dstp, srcp, kc, wpos, srcs, kcs);

  const int node_grid = (NW * 64 + TPB - 1) / TPB;  // 469
  const int agg_grid = (NN * 32 + TPB - 1) / TPB;
  k_node<1><<<node_grid, TPB, 0, stream>>>(x, fc1w, fc1b, h, Wb, Pb4, Pb1, Pr);
  for (int l = 0; l < 3; l++) {
    k_agg<0><<<agg_grid, TPB, 0, stream>>>(rowstart, cnt, icnt, srcs, kcs, Pb4,
                                           Pb1, Pr, cbias, fc2w, fc2b, h, out);
    k_node<0><<<node_grid, TPB, 0, stream>>>(x, fc1w, fc1b, h, Wb, Pb4, Pb1, Pr);
  }
  k_agg<1><<<agg_grid, TPB, 0, stream>>>(rowstart, cnt, icnt, srcs, kcs, Pb4,
                                         Pb1, Pr, cbias, fc2w, fc2b, h, out);
}

// Round 13
// 153.014 us; speedup vs baseline: 1.9944x; 1.0332x over previous
//
#include <hip/hip_runtime.h>

#define NN 30000
#define NE 120000
#define TPB 256
#define SB 118   // ceil(NN/256) scan blocks
#define NW 1875  // node tiles of 16 (NN/16 exact)

typedef __attribute__((ext_vector_type(8))) __bf16 bf16x8;
typedef __attribute__((ext_vector_type(4))) float f32x4;

union B8 { bf16x8 b; unsigned short u[8]; uint4 q; };

__device__ __forceinline__ float blo(unsigned u) { return __uint_as_float(u << 16); }
__device__ __forceinline__ float bhi(unsigned u) { return __uint_as_float(u & 0xffff0000u); }

__device__ __forceinline__ unsigned short f2b(float f) {
  unsigned u = __float_as_uint(f);
  return (unsigned short)((u + 0x7fff + ((u >> 16) & 1)) >> 16);  // RNE
}

// fused: cnt zeroing (blocks 0..117) + MFMA B-fragment weight pack (blocks 118..122)
__global__ void k_init(int* __restrict__ cnt, const float* __restrict__ kw2,
                       const float* __restrict__ kb2, const float* __restrict__ root,
                       uint4* __restrict__ Wb) {
  int bid = blockIdx.x;
  if (bid < SB) {
    int n = bid * TPB + threadIdx.x;
    if (n < NN) cnt[n] = 0;
  } else {
    int f = (bid - SB) * TPB + threadIdx.x;
    if (f >= 1280) return;
    int ct = f >> 6, l = f & 63;
    int j = ct * 16 + (l & 15);
    int k = j >> 5, o = j & 31;
    int i0 = (l >> 4) * 8;
    B8 w;
#pragma unroll
    for (int ii = 0; ii < 8; ii++) {
      int i = i0 + ii;
      float v;
      if (k < 8) v = kw2[k * 1024 + i * 32 + o];
      else if (k == 8) v = kb2[i * 32 + o];
      else v = root[i * 32 + o];
      w.u[ii] = f2b(v);
    }
    Wb[f] = w.q;
  }
}

// kc[e*8+k] = relu(ea@k_w1+k_b1); cnt[dst]++
__global__ void k_prep(const float* __restrict__ ea, const float* __restrict__ w1,
                       const float* __restrict__ b1, const int* __restrict__ dst,
                       float* __restrict__ kc, int* __restrict__ cnt) {
  int e = blockIdx.x * TPB + threadIdx.x;
  if (e >= NE) return;
  float a[6];
#pragma unroll
  for (int i = 0; i < 6; i++) a[i] = ea[e * 6 + i];
#pragma unroll
  for (int k = 0; k < 8; k++) {
    float s = b1[k];
#pragma unroll
    for (int i = 0; i < 6; i++) s = fmaf(a[i], w1[i * 8 + k], s);
    kc[e * 8 + k] = fmaxf(s, 0.f);
  }
  atomicAdd(&cnt[dst[e]], 1);
}

// 3-phase parallel scan
__global__ void k_scan1(const int* __restrict__ cnt, int* __restrict__ bsum) {
  __shared__ int S[TPB];
  int t = threadIdx.x, n = blockIdx.x * TPB + t;
  S[t] = (n < NN) ? cnt[n] : 0;
  __syncthreads();
  for (int off = TPB / 2; off; off >>= 1) {
    if (t < off) S[t] += S[t + off];
    __syncthreads();
  }
  if (t == 0) bsum[blockIdx.x] = S[0];
}

__global__ void k_scan2(int* __restrict__ bsum) {
  __shared__ int S[128];
  int t = threadIdx.x;
  S[t] = (t < SB) ? bsum[t] : 0;
  __syncthreads();
  for (int off = 1; off < 128; off <<= 1) {
    int v = S[t] + ((t >= off) ? S[t - off] : 0);
    __syncthreads();
    S[t] = v;
    __syncthreads();
  }
  if (t < SB) bsum[t] = (t > 0) ? S[t - 1] : 0;
}

__global__ void k_scan3(const int* __restrict__ cnt, const int* __restrict__ bsum,
                        int* __restrict__ rowstart, int* __restrict__ wpos,
                        float* __restrict__ icnt) {
  __shared__ int S[TPB];
  int t = threadIdx.x, n = blockIdx.x * TPB + t;
  int c = (n < NN) ? cnt[n] : 0;
  S[t] = c;
  __syncthreads();
  for (int off = 1; off < TPB; off <<= 1) {
    int v = S[t] + ((t >= off) ? S[t - off] : 0);
    __syncthreads();
    S[t] = v;
    __syncthreads();
  }
  if (n < NN) {
    int r = bsum[blockIdx.x] + S[t] - c;  // exclusive prefix
    rowstart[n] = r;
    wpos[n] = r;
    icnt[n] = 1.f / (float)max(c, 1);
  }
}

// scatter edge payloads into dst-sorted slots: srcs[pos], kcs[pos*8..]
__global__ void k_scatter(const int* __restrict__ dst, const int* __restrict__ src,
                          const float* __restrict__ kc, int* __restrict__ wpos,
                          int* __restrict__ srcs, float* __restrict__ kcs) {
  int e = blockIdx.x * TPB + threadIdx.x;
  if (e >= NE) return;
  int pos = atomicAdd(&wpos[dst[e]], 1);
  srcs[pos] = src[e];
  float4 a = *(const float4*)&kc[e * 8];
  float4 b = *(const float4*)&kc[e * 8 + 4];
  *(float4*)&kcs[(size_t)pos * 8] = a;
  *(float4*)&kcs[(size_t)pos * 8 + 4] = b;
}

// MFMA node transform (R12-verified). Output row now 160 dwords contiguous:
// dwords kp*32+o (kp=0..3) = bf16(k=2kp)|bf16(k=2kp+1)<<16; dwords 128+o = bias row
// (bf16 in low half). Pr separate (f32, read per-node).
template <int FIRST>
__global__ __launch_bounds__(TPB, 4) void k_node(
    const float* __restrict__ x, const float* __restrict__ fc1w,
    const float* __restrict__ fc1b, const float* __restrict__ h,
    const uint4* __restrict__ Wb, unsigned* __restrict__ Pb,
    float* __restrict__ Pr) {
  const int l = threadIdx.x & 63;
  const int wid = blockIdx.x * (TPB / 64) + (threadIdx.x >> 6);
  if (wid >= NW) return;
  const int nb = wid * 16;

  B8 Bf[20];
#pragma unroll
  for (int ct = 0; ct < 20; ct++) Bf[ct].q = Wb[ct * 64 + l];

  // A fragment: lane l holds h[nb + (l&15)][(l>>4)*8 + ii], ii=0..7
  const int row = nb + (l & 15);
  const int k0 = (l >> 4) * 8;
  B8 af;
  if (FIRST) {
    float xv = x[row];
#pragma unroll
    for (int ii = 0; ii < 8; ii++)
      af.u[ii] = f2b(fmaf(xv, fc1w[k0 + ii], fc1b[k0 + ii]));
  } else {
#pragma unroll
    for (int ii = 0; ii < 8; ii++) af.u[ii] = f2b(h[row * 32 + k0 + ii]);
  }

  const int oo = l & 15;
  const int r0 = (l >> 4) * 4;
#pragma unroll
  for (int kp = 0; kp < 4; kp++) {
    f32x4 d0 = {0.f, 0.f, 0.f, 0.f}, d1 = d0, d2 = d0, d3 = d0;
    d0 = __builtin_amdgcn_mfma_f32_16x16x32_bf16(af.b, Bf[4 * kp + 0].b, d0, 0, 0, 0);
    d1 = __builtin_amdgcn_mfma_f32_16x16x32_bf16(af.b, Bf[4 * kp + 1].b, d1, 0, 0, 0);
    d2 = __builtin_amdgcn_mfma_f32_16x16x32_bf16(af.b, Bf[4 * kp + 2].b, d2, 0, 0, 0);
    d3 = __builtin_amdgcn_mfma_f32_16x16x32_bf16(af.b, Bf[4 * kp + 3].b, d3, 0, 0, 0);
#pragma unroll
    for (int r = 0; r < 4; r++) {
      int n = nb + r0 + r;
      Pb[(size_t)n * 160 + kp * 32 + oo] = f2b(d0[r]) | ((unsigned)f2b(d2[r]) << 16);
      Pb[(size_t)n * 160 + kp * 32 + 16 + oo] = f2b(d1[r]) | ((unsigned)f2b(d3[r]) << 16);
    }
  }
  {  // ct 16/17: k=8 bias row -> Pb[..][128+o]; ct 18/19: k=9 root -> Pr (f32)
    f32x4 d0 = {0.f, 0.f, 0.f, 0.f}, d1 = d0, d2 = d0, d3 = d0;
    d0 = __builtin_amdgcn_mfma_f32_16x16x32_bf16(af.b, Bf[16].b, d0, 0, 0, 0);
    d1 = __builtin_amdgcn_mfma_f32_16x16x32_bf16(af.b, Bf[17].b, d1, 0, 0, 0);
    d2 = __builtin_amdgcn_mfma_f32_16x16x32_bf16(af.b, Bf[18].b, d2, 0, 0, 0);
    d3 = __builtin_amdgcn_mfma_f32_16x16x32_bf16(af.b, Bf[19].b, d3, 0, 0, 0);
#pragma unroll
    for (int r = 0; r < 4; r++) {
      int n = nb + r0 + r;
      Pb[(size_t)n * 160 + 128 + oo] = f2b(d0[r]);
      Pb[(size_t)n * 160 + 128 + 16 + oo] = f2b(d1[r]);
      Pr[(size_t)n * 32 + oo] = d2[r];
      Pr[(size_t)n * 32 + 16 + oo] = d3[r];
    }
  }
}

// CSR aggregate: ONE WAVE PER NODE, two edges in flight (halves), uniform trip
// count ceil(deg/2) -> no divergence. Final cross-half merge via shfl_xor(32).
template <int FINAL>
__global__ void k_agg(const int* __restrict__ rowstart, const int* __restrict__ cnt,
                      const float* __restrict__ icnt, const int* __restrict__ srcs,
                      const float* __restrict__ kcs, const unsigned* __restrict__ Pb,
                      const float* __restrict__ Pr, const float* __restrict__ cbias,
                      const float* __restrict__ fc2w, const float* __restrict__ fc2b,
                      float* __restrict__ h, float* __restrict__ out) {
  int t = blockIdx.x * TPB + threadIdx.x;
  int n = t >> 6;  // one 64-lane wave per node
  if (n >= NN) return;
  int lane = threadIdx.x & 63;
  int half = lane >> 5, o = lane & 31;
  int rs = rowstart[n], re = rs + cnt[n];
  float acc = 0.f;
  for (int j = rs + half; j < re; j += 2) {
    int s = srcs[j];
    float ck = (o < 8) ? kcs[(size_t)j * 8 + o] : 0.f;
    const unsigned* Ps = Pb + (size_t)s * 160;
    unsigned w0 = Ps[o], w1 = Ps[32 + o], w2 = Ps[64 + o], w3 = Ps[96 + o];
    unsigned wb = Ps[128 + o];
    acc += blo(wb);  // bias row, coefficient 1
    acc = fmaf(__shfl(ck, 0, 32), blo(w0), acc);
    acc = fmaf(__shfl(ck, 1, 32), bhi(w0), acc);
    acc = fmaf(__shfl(ck, 2, 32), blo(w1), acc);
    acc = fmaf(__shfl(ck, 3, 32), bhi(w1), acc);
    acc = fmaf(__shfl(ck, 4, 32), blo(w2), acc);
    acc = fmaf(__shfl(ck, 5, 32), bhi(w2), acc);
    acc = fmaf(__shfl(ck, 6, 32), blo(w3), acc);
    acc = fmaf(__shfl(ck, 7, 32), bhi(w3), acc);
  }
  acc += __shfl_xor(acc, 32, 64);  // merge halves
  float hv = fmaxf(fmaf(acc, icnt[n], Pr[(size_t)n * 32 + o] + cbias[o]), 0.f);
  if (FINAL) {
    float s2 = hv * fc2w[o];
#pragma unroll
    for (int d = 16; d; d >>= 1) s2 += __shfl_xor(s2, d, 32);
    if (lane == 0) out[n] = s2 + fc2b[0];
  } else {
    if (lane < 32) h[(size_t)n * 32 + o] = hv;
  }
}

extern "C" void kernel_launch(void* const* d_in, const int* in_sizes, int n_in,
                              void* d_out, int out_size, void* d_ws, size_t ws_size,
                              hipStream_t stream) {
  const float* x     = (const float*)d_in[0];
  const int*   ei    = (const int*)d_in[1];
  const float* ea    = (const float*)d_in[2];
  const float* fc1w  = (const float*)d_in[3];
  const float* fc1b  = (const float*)d_in[4];
  const float* kw1   = (const float*)d_in[5];
  const float* kb1   = (const float*)d_in[6];
  const float* kw2   = (const float*)d_in[7];
  const float* kb2   = (const float*)d_in[8];
  const float* root  = (const float*)d_in[9];
  const float* cbias = (const float*)d_in[10];
  const float* fc2w  = (const float*)d_in[11];
  const float* fc2b  = (const float*)d_in[12];
  float* out = (float*)d_out;
  const int* srcp = ei;
  const int* dstp = ei + NE;

  float* ws = (float*)d_ws;
  float* kc       = ws;                        // NE*8
  float* kcs      = kc + NE * 8;               // NE*8
  int*   srcs     = (int*)(kcs + NE * 8);      // NE
  float* icnt     = (float*)(srcs + NE);       // NN
  float* h        = icnt + NN;                 // NN*32
  float* Pr       = h + NN * 32;               // NN*32
  int*   cnt      = (int*)(Pr + NN * 32);      // NN
  int*   rowstart = cnt + NN;                  // NN
  int*   wpos     = rowstart + NN;             // NN
  int*   bsum     = wpos + NN;                 // 128
  uint4* Wb       = (uint4*)(bsum + 128);      // 1280 uint4 (20KB), 16B-aligned
  unsigned* Pb    = (unsigned*)(Wb + 1280);    // NN*160

  k_init<<<SB + 5, TPB, 0, stream>>>(cnt, kw2, kb2, root, Wb);
  k_prep<<<(NE + TPB - 1) / TPB, TPB, 0, stream>>>(ea, kw1, kb1, dstp, kc, cnt);
  k_scan1<<<SB, TPB, 0, stream>>>(cnt, bsum);
  k_scan2<<<1, 128, 0, stream>>>(bsum);
  k_scan3<<<SB, TPB, 0, stream>>>(cnt, bsum, rowstart, wpos, icnt);
  k_scatter<<<(NE + TPB - 1) / TPB, TPB, 0, stream>>>(dstp, srcp, kc, wpos, srcs, kcs);

  const int node_grid = (NW * 64 + TPB - 1) / TPB;   // 469
  const int agg_grid = (NN * 64 + TPB - 1) / TPB;    // 7500
  k_node<1><<<node_grid, TPB, 0, stream>>>(x, fc1w, fc1b, h, Wb, Pb, Pr);
  for (int l = 0; l < 3; l++) {
    k_agg<0><<<agg_grid, TPB, 0, stream>>>(rowstart, cnt, icnt, srcs, kcs, Pb,
                                           Pr, cbias, fc2w, fc2b, h, out);
    k_node<0><<<node_grid, TPB, 0, stream>>>(x, fc1w, fc1b, h, Wb, Pb, Pr);
  }
  k_agg<1><<<agg_grid, TPB, 0, stream>>>(rowstart, cnt, icnt, srcs, kcs, Pb,
                                         Pr, cbias, fc2w, fc2b, h, out);
}